// Round 7
// baseline (299.012 us; speedup 1.0000x reference)
//
#include <hip/hip_runtime.h>
#include <hip/hip_bf16.h>
#include <math.h>

#define BB 128    // batch
#define NN 96     // perturbations
#define DD 3072   // C*H*W
#define KK 10     // classes
#define SPL 8     // waves per block in k1b
#define KST 12    // MFMA K-steps per wave: 3072 / (SPL*32)
#define H_TOT (NN * BB * 384)   // 4,718,592 8-float items
#define H_STRIDE (2048 * 256)   // grid stride -> exactly 9 items/thread

typedef short s16x8 __attribute__((ext_vector_type(8)));
typedef float f32x4 __attribute__((ext_vector_type(4)));

// ------- Kernel 1a: fill-shaped streaming producer (+ fused W-pack) -------
// Pure BW shape: 2048 blocks x 256 threads, grid-stride, 32B contiguous
// read of deltas per thread-item (wave reads 2KB contiguous; block walks a
// long slab) — the same structure the 87us/6.9TB/s harness fill uses.
// Each item h -> (row=h/384, d8=h%384): computes 8 bf16 of
// clip(imgs+deltas) and stores ONE 16B A-fragment record of xp:
//   xp rec index = (tile*96 + sg)*64 + lane,  tile=row>>4, m=row&15,
//   sg=d8>>2, q=d8&3, lane=q*16+m   (bijective in h).
// Blocks 0..23 also pack W into pwg (old k0), block 0 zeroes the counter.
__global__ __launch_bounds__(256) void k1a_stream(
    const float* __restrict__ imgs,    // (128, 3072)
    const float* __restrict__ deltas,  // (96, 128, 3072)
    const float* __restrict__ W,       // (3072, 10)
    unsigned short* __restrict__ pwg,  // packed W (96 KB)
    unsigned short* __restrict__ xp,   // packed A (75.5 MB)
    unsigned int* __restrict__ counter)
{
    if (blockIdx.x == 0 && threadIdx.x == 0) *counter = 0u;
    if (blockIdx.x < 24) {   // fused k0_pack
        const int r = blockIdx.x * 256 + threadIdx.x;   // 0..6143
        const int col  = r & 15;
        const int quad = (r >> 4) & 3;
        const int kb   = r >> 6;
        union { unsigned short us[8]; uint4 v; } rec;
#pragma unroll
        for (int j = 0; j < 8; ++j) {
            const int k = kb * 32 + quad * 8 + j;
            const float v = (col < KK) ? W[k * KK + col] : 0.0f;
            const __hip_bfloat16 h = __float2bfloat16(v);
            __builtin_memcpy(&rec.us[j], &h, 2);
        }
        ((uint4*)pwg)[r] = rec.v;
    }

    int h = blockIdx.x * 256 + threadIdx.x;
#pragma unroll 1
    for (int it = 0; it < 9; ++it, h += H_STRIDE) {
        const int row = h / 384;          // n*128 + b
        const int d8  = h - row * 384;    // 0..383
        const float* dp = deltas + (size_t)h * 8;
        const float* ip = imgs + (size_t)(row & 127) * DD + d8 * 8;
        const f32x4 da = *(const f32x4*)(dp);
        const f32x4 db = *(const f32x4*)(dp + 4);
        const f32x4 ia = *(const f32x4*)(ip);
        const f32x4 ib = *(const f32x4*)(ip + 4);
        s16x8 afrag;
#pragma unroll
        for (int j = 0; j < 4; ++j) {
            const float x0 = fminf(fmaxf(da[j] + ia[j], 0.f), 1.f);
            const float x1 = fminf(fmaxf(db[j] + ib[j], 0.f), 1.f);
            const __hip_bfloat16 h0 = __float2bfloat16(x0);
            const __hip_bfloat16 h1 = __float2bfloat16(x1);
            unsigned short us0, us1;
            __builtin_memcpy(&us0, &h0, 2);
            __builtin_memcpy(&us1, &h1, 2);
            afrag[j]     = (short)us0;
            afrag[j + 4] = (short)us1;
        }
        const int tile = row >> 4;
        const int m    = row & 15;
        const int sg   = d8 >> 2;
        const int q    = d8 & 3;
        *(s16x8*)(xp + (((size_t)tile * 96 + sg) * 64 + (q * 16 + m)) * 8) = afrag;
    }
}

// ---------------- Kernel 1b: MFMA logits + per-(n,b) losses ----------------
// R0-proven structure; A-frags now single coalesced 16B loads from the
// L3-resident xp (identical addressing to the pwg B-loads). Accumulation
// order bit-identical to the R0 kernel.
__global__ __launch_bounds__(512) void k1b_mfma(
    const unsigned short* __restrict__ xp,
    const unsigned short* __restrict__ pwg,
    const float* __restrict__ bias,    // (10)
    const int*   __restrict__ labels,  // (128)
    float* __restrict__ l1_ws,         // (128, 96)
    float* __restrict__ l2_ws)         // (128, 96)
{
    const int lane = threadIdx.x & 63;
    const int wv   = threadIdx.x >> 6;      // 0..7 = K-split
    const int tile = blockIdx.x;            // 0..767
    const int r0   = tile * 16;
    const int n    = r0 >> 7;               // constant over tile
    const int b0   = r0 & 127;
    const int m    = lane & 15;
    const int quad = lane >> 4;

    const unsigned short* ap = xp + (((size_t)tile * 96 + wv * KST) * 64 + lane) * 8;
    const unsigned short* wp = pwg + ((size_t)(wv * KST) * 64 + lane) * 8;

    f32x4 acc = {0.f, 0.f, 0.f, 0.f};
#pragma unroll 2
    for (int s = 0; s < KST; ++s) {
        const s16x8 afrag = *(const s16x8*)(ap);
        const s16x8 bfrag = *(const s16x8*)(wp);
        acc = __builtin_amdgcn_mfma_f32_16x16x32_bf16(afrag, bfrag, acc, 0, 0, 0);
        ap += 512; wp += 512;
    }

    // C layout (m89-verified): col = lane&15, row = quad*4 + reg.
    __shared__ float sred[SPL][16][16];     // 8 KB
#pragma unroll
    for (int reg = 0; reg < 4; ++reg)
        sred[wv][quad * 4 + reg][m] = acc[reg];
    __syncthreads();

    if (wv == 0 && lane < 16) {
        const int rr = lane;                // tile row -> b = b0+rr
        float lg[KK];
#pragma unroll
        for (int k = 0; k < KK; ++k) {
            float s = 0.f;
#pragma unroll
            for (int sp = 0; sp < SPL; ++sp) s += sred[sp][rr][k];
            lg[k] = s + bias[k];
        }
        // top-1 (first max -> lower index on ties, matches lax.top_k)
        int top1 = 0; float m1 = lg[0];
#pragma unroll
        for (int k = 1; k < KK; ++k) if (lg[k] > m1) { m1 = lg[k]; top1 = k; }
        int sec = (top1 == 0) ? 1 : 0; float m2 = lg[sec];
#pragma unroll
        for (int k = 0; k < KK; ++k)
            if (k != top1 && lg[k] > m2) { m2 = lg[k]; sec = k; }
        float se = 0.f;
#pragma unroll
        for (int k = 0; k < KK; ++k) se += expf(lg[k] - m1);
        const float lse = m1 + logf(se);
        const int b = b0 + rr;
        const int lab = labels[b];
        const float loss1 = lse - lg[lab];
        const float loss2 = (top1 == lab) ? (lse - lg[sec]) : -10000.0f;
        l1_ws[b * NN + n] = loss1;
        l2_ws[b * NN + n] = loss2;
    }
}

// ---------------- Kernel 2: per-b selection + fused final mean ----------------
__global__ __launch_bounds__(128) void k2_select(
    const float* __restrict__ l1_ws, const float* __restrict__ l2_ws,
    const int* __restrict__ ind_p, float* __restrict__ perb,
    unsigned int* __restrict__ counter, float* __restrict__ out)
{
    const int b = blockIdx.x;
    const int t = threadIdx.x;
    __shared__ float sd[NN];
    __shared__ float sl2[NN];
    __shared__ float ssel;
    __shared__ float swsum[2];
    __shared__ unsigned int slast;

    float myl1 = 0.f, myd = 0.f;
    if (t < NN) {
        const float a = l1_ws[b * NN + t];
        const float c = l2_ws[b * NN + t];
        myl1 = a; myd = a - c;
        sd[t] = myd; sl2[t] = c;
    }
    __syncthreads();

    if (t < NN) {
        int rank = 0;
        for (int j = 0; j < NN; ++j) {
            const float dj = sd[j];
            rank += (dj < myd) || (dj == myd && j < t);  // stable argsort
        }
        if (rank == ind_p[0]) ssel = sl2[t];
    }

    float s = myl1;
#pragma unroll
    for (int off = 32; off >= 1; off >>= 1) s += __shfl_down(s, off, 64);
    if ((t & 63) == 0) swsum[t >> 6] = s;
    __syncthreads();
    if (t == 0) {
        const float total = swsum[0] + swsum[1];
        perb[b] = total / 96.0f - ssel;
        __threadfence();                       // publish perb[b] device-wide
        const unsigned int prev = atomicAdd(counter, 1u);
        slast = (prev == BB - 1) ? 1u : 0u;    // am I the last block?
    }
    __syncthreads();

    if (slast) {
        __threadfence();                       // acquire other blocks' perb
        float v = perb[t];                     // t in 0..127
#pragma unroll
        for (int off = 32; off >= 1; off >>= 1) v += __shfl_down(v, off, 64);
        if ((t & 63) == 0) swsum[t >> 6] = v;
        __syncthreads();
        if (t == 0) out[0] = (swsum[0] + swsum[1]) / 128.0f;
    }
}

extern "C" void kernel_launch(void* const* d_in, const int* in_sizes, int n_in,
                              void* d_out, int out_size, void* d_ws, size_t ws_size,
                              hipStream_t stream) {
    const float* imgs   = (const float*)d_in[0];
    const float* deltas = (const float*)d_in[1];
    const float* W      = (const float*)d_in[2];
    const float* bias   = (const float*)d_in[3];
    const int*   labels = (const int*)d_in[4];
    const int*   ind    = (const int*)d_in[5];
    float* out = (float*)d_out;

    float* l1_ws = (float*)d_ws;                   // 12288 floats
    float* l2_ws = l1_ws + NN * BB;                // 12288 floats
    float* perb  = l2_ws + NN * BB;                // 128 floats
    unsigned int* counter = (unsigned int*)(perb + BB);   // 1 uint (zeroed in k1a)
    unsigned short* pwg = (unsigned short*)(counter + 4); // 96 KB packed W
    unsigned short* xp  = pwg + (size_t)6144 * 8;         // 75.5 MB packed A

    k1a_stream<<<dim3(2048), dim3(256), 0, stream>>>(
        imgs, deltas, W, pwg, xp, counter);
    k1b_mfma<<<dim3(768), dim3(512), 0, stream>>>(
        xp, pwg, bias, labels, l1_ws, l2_ws);
    k2_select<<<dim3(BB), dim3(128), 0, stream>>>(
        l1_ws, l2_ws, ind, perb, counter, out);
}

// Round 8
// 243.765 us; speedup vs baseline: 1.2266x; 1.2266x over previous
//
#include <hip/hip_runtime.h>
#include <hip/hip_bf16.h>
#include <math.h>

#define BB 128    // batch
#define NN 96     // perturbations
#define DD 3072   // C*H*W
#define KK 10     // classes
#define SPL 8     // waves per block in k1
#define W_CH 256  // floats of D per row per staged chunk (1 KB/row)
#define NCH 12    // 3072 / 256 chunks

typedef short s16x8 __attribute__((ext_vector_type(8)));
typedef float f32x4 __attribute__((ext_vector_type(4)));

// ---------------- Kernel 0: pack W into B-fragment layout ----------------
// Record r (0..6143): col=r&15, quad=(r>>4)&3, kb=r>>6. 16B record holds
// bf16 W[kb*32+quad*8+j][col], j=0..7 (zero for col>=10). Lane `l` of
// K-block kb then reads record kb*64+l with ONE coalesced dwordx4.
// Also zeroes the k2 completion counter (workspace poisoned each iter).
__global__ __launch_bounds__(256) void k0_pack(
    const float* __restrict__ W, unsigned short* __restrict__ pwg,
    unsigned int* __restrict__ counter)
{
    if (blockIdx.x == 0 && threadIdx.x == 0) *counter = 0u;
    const int r = blockIdx.x * 256 + threadIdx.x;   // 0..6143
    const int col  = r & 15;
    const int quad = (r >> 4) & 3;
    const int kb   = r >> 6;
    union { unsigned short us[8]; uint4 v; } rec;
#pragma unroll
    for (int j = 0; j < 8; ++j) {
        const int k = kb * 32 + quad * 8 + j;
        const float v = (col < KK) ? W[k * KK + col] : 0.0f;
        const __hip_bfloat16 h = __float2bfloat16(v);
        __builtin_memcpy(&rec.us[j], &h, 2);
    }
    ((uint4*)pwg)[r] = rec.v;
}

// ---------------- Kernel 1: MFMA logits + per-(n,b) losses ----------------
// v5: R6's double-buffered LDS staging, but deltas staged via the async
// global->LDS DMA path (__builtin_amdgcn_global_load_lds, width 16).
// Rationale (R7 probe): reads are pinned at 2.0-2.2 TB/s across ALL
// VGPR-round-trip structures (fragment-direct, reg-staged LDS, pure
// fill-shaped stream), while the write path runs 6.9 TB/s. global_load_lds
// is the one mechanically distinct read type: fire-and-forget, no VGPR
// writeback, vmcnt-tracked — the closest analog to the store path.
// Geometry per wave per chunk: 2 DMA ops, each = uniform LDS row base +
// lane*16B (m104 constraint satisfied), global source per-lane contiguous
// (row r0+2wv+{0,1}, 1KB). Compute/reduce/epilogue identical to R6
// (verified absmax 0.0).
__global__ __launch_bounds__(512) void k1_mfma(
    const float* __restrict__ imgs,    // (128, 3072)
    const float* __restrict__ deltas,  // (96, 128, 3072)
    const unsigned short* __restrict__ pwg,
    const float* __restrict__ bias,    // (10)
    const int*   __restrict__ labels,  // (128)
    float* __restrict__ l1_ws,         // (128, 96)
    float* __restrict__ l2_ws)         // (128, 96)
{
    const int lane = threadIdx.x & 63;
    const int wv   = threadIdx.x >> 6;      // 0..7
    const int tile = blockIdx.x;            // 0..767
    const int r0   = tile * 16;
    const int n    = r0 >> 7;               // constant over tile
    const int b0   = r0 & 127;
    const int m    = lane & 15;             // A row within tile
    const int quad = lane >> 4;

    __shared__ float ldsD[2][16][W_CH];     // 32 KB double-buffered deltas
    __shared__ float sred[SPL][16][16];     // 8 KB

    // DMA staging identity: wave wv stages rows 2wv and 2wv+1 of each chunk.
    // Global source: per-lane 16B (lane*4 floats); LDS dest: uniform row base
    // (HW scatters lane i at base + 16*i).
    const float* gsA = deltas + (size_t)(r0 + 2 * wv)     * DD + lane * 4;
    const float* gsB = deltas + (size_t)(r0 + 2 * wv + 1) * DD + lane * 4;

    // compute identity: wave wv handles K-slice c*256 + wv*32 + [0,32)
    const float* ipb = imgs + (size_t)(b0 + m) * DD + wv * 32 + quad * 8;
    const unsigned short* wpb = pwg + ((size_t)wv * 64 + lane) * 8;
    const int uf = wv * 32 + quad * 8;      // float offset in LDS row

    // prologue: DMA chunk 0 into buf 0
    __builtin_amdgcn_global_load_lds(
        (const __attribute__((address_space(1))) void*)(gsA),
        (__attribute__((address_space(3))) void*)&ldsD[0][2 * wv][0], 16, 0, 0);
    __builtin_amdgcn_global_load_lds(
        (const __attribute__((address_space(1))) void*)(gsB),
        (__attribute__((address_space(3))) void*)&ldsD[0][2 * wv + 1][0], 16, 0, 0);
    __syncthreads();

    f32x4 acc = {0.f, 0.f, 0.f, 0.f};
#pragma unroll 1
    for (int c = 0; c < NCH; ++c) {
        const int cb = c & 1;
        if (c + 1 < NCH) {   // DMA next chunk into the other buffer
            __builtin_amdgcn_global_load_lds(
                (const __attribute__((address_space(1))) void*)(gsA + (c + 1) * W_CH),
                (__attribute__((address_space(3))) void*)&ldsD[cb ^ 1][2 * wv][0], 16, 0, 0);
            __builtin_amdgcn_global_load_lds(
                (const __attribute__((address_space(1))) void*)(gsB + (c + 1) * W_CH),
                (__attribute__((address_space(3))) void*)&ldsD[cb ^ 1][2 * wv + 1][0], 16, 0, 0);
        }
        // compute chunk c from LDS
        const f32x4 dv0 = *(const f32x4*)&ldsD[cb][m][uf];
        const f32x4 dv1 = *(const f32x4*)&ldsD[cb][m][uf + 4];
        const f32x4 iv0 = *(const f32x4*)(ipb + c * W_CH);
        const f32x4 iv1 = *(const f32x4*)(ipb + c * W_CH + 4);
        const s16x8 bfrag = *(const s16x8*)(wpb + (size_t)c * 4096);
        s16x8 afrag;
#pragma unroll
        for (int j = 0; j < 4; ++j) {
            const float xc0 = fminf(fmaxf(dv0[j] + iv0[j], 0.f), 1.f);
            const float xc1 = fminf(fmaxf(dv1[j] + iv1[j], 0.f), 1.f);
            const __hip_bfloat16 h0 = __float2bfloat16(xc0);
            const __hip_bfloat16 h1 = __float2bfloat16(xc1);
            unsigned short us0, us1;
            __builtin_memcpy(&us0, &h0, 2);
            __builtin_memcpy(&us1, &h1, 2);
            afrag[j]     = (short)us0;
            afrag[j + 4] = (short)us1;
        }
        acc = __builtin_amdgcn_mfma_f32_16x16x32_bf16(afrag, bfrag, acc, 0, 0, 0);
        __syncthreads();   // drains DMA (compiler emits vmcnt(0) before barrier)
    }

    // C layout (m89-verified): col = lane&15, row = quad*4 + reg.
#pragma unroll
    for (int reg = 0; reg < 4; ++reg)
        sred[wv][quad * 4 + reg][m] = acc[reg];
    __syncthreads();

    if (wv == 0 && lane < 16) {
        const int rr = lane;                // tile row -> b = b0+rr
        float lg[KK];
#pragma unroll
        for (int k = 0; k < KK; ++k) {
            float s = 0.f;
#pragma unroll
            for (int sp = 0; sp < SPL; ++sp) s += sred[sp][rr][k];
            lg[k] = s + bias[k];
        }
        // top-1 (first max -> lower index on ties, matches lax.top_k)
        int top1 = 0; float m1 = lg[0];
#pragma unroll
        for (int k = 1; k < KK; ++k) if (lg[k] > m1) { m1 = lg[k]; top1 = k; }
        int sec = (top1 == 0) ? 1 : 0; float m2 = lg[sec];
#pragma unroll
        for (int k = 0; k < KK; ++k)
            if (k != top1 && lg[k] > m2) { m2 = lg[k]; sec = k; }
        float se = 0.f;
#pragma unroll
        for (int k = 0; k < KK; ++k) se += expf(lg[k] - m1);
        const float lse = m1 + logf(se);
        const int b = b0 + rr;
        const int lab = labels[b];
        const float loss1 = lse - lg[lab];
        const float loss2 = (top1 == lab) ? (lse - lg[sec]) : -10000.0f;
        l1_ws[b * NN + n] = loss1;
        l2_ws[b * NN + n] = loss2;
    }
}

// ---------------- Kernel 2: per-b selection + fused final mean ----------------
__global__ __launch_bounds__(128) void k2_select(
    const float* __restrict__ l1_ws, const float* __restrict__ l2_ws,
    const int* __restrict__ ind_p, float* __restrict__ perb,
    unsigned int* __restrict__ counter, float* __restrict__ out)
{
    const int b = blockIdx.x;
    const int t = threadIdx.x;
    __shared__ float sd[NN];
    __shared__ float sl2[NN];
    __shared__ float ssel;
    __shared__ float swsum[2];
    __shared__ unsigned int slast;

    float myl1 = 0.f, myd = 0.f;
    if (t < NN) {
        const float a = l1_ws[b * NN + t];
        const float c = l2_ws[b * NN + t];
        myl1 = a; myd = a - c;
        sd[t] = myd; sl2[t] = c;
    }
    __syncthreads();

    if (t < NN) {
        int rank = 0;
        for (int j = 0; j < NN; ++j) {
            const float dj = sd[j];
            rank += (dj < myd) || (dj == myd && j < t);  // stable argsort
        }
        if (rank == ind_p[0]) ssel = sl2[t];
    }

    float s = myl1;
#pragma unroll
    for (int off = 32; off >= 1; off >>= 1) s += __shfl_down(s, off, 64);
    if ((t & 63) == 0) swsum[t >> 6] = s;
    __syncthreads();
    if (t == 0) {
        const float total = swsum[0] + swsum[1];
        perb[b] = total / 96.0f - ssel;
        __threadfence();                       // publish perb[b] device-wide
        const unsigned int prev = atomicAdd(counter, 1u);
        slast = (prev == BB - 1) ? 1u : 0u;    // am I the last block?
    }
    __syncthreads();

    if (slast) {
        __threadfence();                       // acquire other blocks' perb
        float v = perb[t];                     // t in 0..127
#pragma unroll
        for (int off = 32; off >= 1; off >>= 1) v += __shfl_down(v, off, 64);
        if ((t & 63) == 0) swsum[t >> 6] = v;
        __syncthreads();
        if (t == 0) out[0] = (swsum[0] + swsum[1]) / 128.0f;
    }
}

extern "C" void kernel_launch(void* const* d_in, const int* in_sizes, int n_in,
                              void* d_out, int out_size, void* d_ws, size_t ws_size,
                              hipStream_t stream) {
    const float* imgs   = (const float*)d_in[0];
    const float* deltas = (const float*)d_in[1];
    const float* W      = (const float*)d_in[2];
    const float* bias   = (const float*)d_in[3];
    const int*   labels = (const int*)d_in[4];
    const int*   ind    = (const int*)d_in[5];
    float* out = (float*)d_out;

    float* l1_ws = (float*)d_ws;                   // 12288 floats
    float* l2_ws = l1_ws + NN * BB;                // 12288 floats
    float* perb  = l2_ws + NN * BB;                // 128 floats
    unsigned int* counter = (unsigned int*)(perb + BB);   // 1 uint (zeroed in k0)
    unsigned short* pwg = (unsigned short*)(counter + 4); // 96 KB packed W

    k0_pack<<<dim3(24), dim3(256), 0, stream>>>(W, pwg, counter);
    k1_mfma<<<dim3(768), dim3(512), 0, stream>>>(
        imgs, deltas, pwg, bias, labels, l1_ws, l2_ws);
    k2_select<<<dim3(BB), dim3(128), 0, stream>>>(
        l1_ws, l2_ws, ind, perb, counter, out);
}